// Round 1
// baseline (2293.398 us; speedup 1.0000x reference)
//
#include <hip/hip_runtime.h>

// LightGCN forward on MI355X — slab-bucketed edges + LDS-resident scatter-accumulate.
// Inputs: d_in[0] = edge_index int32 [2, E]; d_in[1] = emb_weight f32 [N, 64].
// Output: d_out = [emb0 (N*64) | out (N*64)] f32, out = mean(emb0..emb3).
// Assumes N <= 131072 (<=256 buckets of 512 nodes). Here N=120000, E=2M, dst ~uniform.
//
// Design change vs previous version: the per-node CSR gather (c3_build sort + col[]
// + one-wave-per-node loops with ~1.5x tail-slot waste) is replaced by one WG per
// 512-node bucket holding the full fp32 accumulator in LDS (512*64*4 = 128 KB) and
// streaming the *unsorted* slab edge list: zero slot waste, perfect balance,
// register-free accumulation via ds_add_f32 (bank-conflict-free by half-swap).

#define DIM 64
#define BN 512          // nodes per bucket
#define BSH 9
#define CHUNK 8192      // edges per c1 workgroup

typedef unsigned short u16;
typedef unsigned int u32;

static __device__ __forceinline__ float bf2f_lo(u32 p) { return __uint_as_float(p << 16); }
static __device__ __forceinline__ float bf2f_hi(u32 p) { return __uint_as_float(p & 0xffff0000u); }
static __device__ __forceinline__ u16 f2bf(float f) {   // round-to-nearest-even
    unsigned u = __float_as_uint(f);
    return (u16)((u + 0x7fffu + ((u >> 16) & 1u)) >> 16);
}
static __device__ __forceinline__ u32 pack2(float a, float b) {
    return (u32)f2bf(a) | ((u32)f2bf(b) << 16);
}

__global__ void zero_cur(int* __restrict__ cursor) { cursor[threadIdx.x] = 0; }

// Per-chunk LDS counting-sort by bucket; slab space reserved with one global
// atomicAdd per (chunk,bucket). Unchanged from previous version (known-good).
__global__ void __launch_bounds__(512) c1_scatter(
        const int* __restrict__ src, const int* __restrict__ dst,
        int* __restrict__ cursor, u32* __restrict__ slab, int E, int CAP) {
    __shared__ u32 buf[CHUNK];
    __shared__ unsigned char bb[CHUNK];
    __shared__ int posb[256], startb[256], gbase[256];
    int w = blockIdx.x, tid = threadIdx.x;
    int lo = w * CHUNK, hi = min(lo + CHUNK, E);
    if (tid < 256) posb[tid] = 0;
    __syncthreads();
    for (int i = lo + tid; i < hi; i += 512) atomicAdd(&posb[dst[i] >> BSH], 1);
    __syncthreads();
    int x = 0;
    if (tid < 256) {
        x = posb[tid];
        gbase[tid] = x ? atomicAdd(cursor + tid, x) : 0;   // slab reservation
    }
    __syncthreads();
    for (int off = 1; off < 256; off <<= 1) {              // in-place scan of posb
        int t = (tid >= off && tid < 256) ? posb[tid - off] : 0;
        __syncthreads();
        if (tid < 256) posb[tid] += t;
        __syncthreads();
    }
    if (tid < 256) startb[tid] = posb[tid] - x;
    __syncthreads();
    if (tid < 256) posb[tid] = startb[tid];                // placement cursor
    __syncthreads();
    for (int i = lo + tid; i < hi; i += 512) {
        int d = dst[i], b = d >> BSH;
        int q = atomicAdd(&posb[b], 1);
        buf[q] = ((u32)src[i] << BSH) | (u32)(d & (BN - 1));
        bb[q] = (unsigned char)b;
    }
    __syncthreads();
    int n = hi - lo;
    for (int q = tid; q < n; q += 512) {                   // coalesced bucket-run writes
        int b = bb[q];
        slab[(size_t)b * CAP + gbase[b] + (q - startb[b])] = buf[q];
    }
}

// Per-bucket local-dst histogram -> dis = rsqrt(deg). Replaces all of c3_build.
__global__ void __launch_bounds__(256) c2_deg(
        const u32* __restrict__ slab, const int* __restrict__ cursor,
        float* __restrict__ dis, int N, int CAP) {
    __shared__ int cnt[BN];
    int b = blockIdx.x, tid = threadIdx.x;
    cnt[tid] = 0; cnt[tid + 256] = 0;
    __syncthreads();
    int n = cursor[b];
    const u32* sp = slab + (size_t)b * CAP;
    for (int i = tid; i < n; i += 256) atomicAdd(&cnt[sp[i] & (BN - 1)], 1);
    __syncthreads();
    int base = b << BSH;
    int nLoc = min(BN, N - base);
    for (int i = tid; i < nLoc; i += 256) {
        int c = cnt[i];
        dis[base + i] = c ? rsqrtf((float)c) : 0.f;
    }
}

// e0b = bf16(dis * emb0) prescaled table; also emits the exact f32 emb0 output.
__global__ void cvt_copy(const float4* __restrict__ emb, const float* __restrict__ dis,
                         ushort4* __restrict__ e0b, float4* __restrict__ emb0_out, int n4) {
    int i = blockIdx.x * blockDim.x + threadIdx.x;
    if (i < n4) {
        float4 v = emb[i];
        float w = dis[i >> 4];
        ushort4 o;
        o.x = f2bf(w * v.x); o.y = f2bf(w * v.y);
        o.z = f2bf(w * v.z); o.w = f2bf(w * v.w);
        e0b[i] = o;
        emb0_out[i] = v;
    }
}

// Streaming scatter-accumulate into the bucket's LDS accumulator.
// Wave halves process 2 edges per step; 8-deep unroll keeps ~16 row fetches in
// flight per wave. ds_add bank pattern: half0 writes even dims first, half1 odd
// dims first -> every ds_add instruction is exactly 2 lanes/bank (free, m136)
// and same-address lane collisions within an instruction are impossible.
template<int INS>
static __device__ __forceinline__ void scat_accum(
        const u32* __restrict__ sp, int cnt, const u32* __restrict__ tab,
        float* __restrict__ acc, int tid) {
    int wv = tid >> 6, lane = tid & 63;
    int half = lane >> 5, d2 = lane & 31;
    int chunk = (cnt + 15) >> 4;                 // ceil(cnt/16) edges per wave
    int s0 = wv * chunk;
    int s1 = min(s0 + chunk, cnt);
    s0 = __builtin_amdgcn_readfirstlane(s0);
    s1 = __builtin_amdgcn_readfirstlane(s1);
    int cmax = cnt - 1;                          // loops skipped entirely if cnt==0
    int e = s0;
    for (; e + 16 <= s1; e += 16) {              // full 8-pair rounds, no predication
        u32 sv[8], p[8];
#pragma unroll
        for (int k = 0; k < 8; ++k) sv[k] = sp[e + 2 * k + half];
#pragma unroll
        for (int k = 0; k < 8; ++k) p[k] = tab[(int)(sv[k] >> BSH) * INS + d2];
#pragma unroll
        for (int k = 0; k < 8; ++k) {
            u32 v = p[k];
            float lo = bf2f_lo(v), hi = bf2f_hi(v);
            float a0 = half ? hi : lo;           // value for dim 2*d2 + half
            float a1 = half ? lo : hi;           // value for dim 2*d2 + 1 - half
            int ld = (int)(sv[k] & (BN - 1));
            float* bp = &acc[ld * DIM + 2 * d2];
            atomicAdd(bp + half, a0);
            atomicAdd(bp + 1 - half, a1);
        }
    }
    if (e < s1) {                                // single predicated tail round
        u32 sv[8], p[8];
#pragma unroll
        for (int k = 0; k < 8; ++k) sv[k] = sp[min(e + 2 * k + half, cmax)];
#pragma unroll
        for (int k = 0; k < 8; ++k) p[k] = tab[(int)(sv[k] >> BSH) * INS + d2];
#pragma unroll
        for (int k = 0; k < 8; ++k) {
            int ee = e + 2 * k + half;
            if (ee < s1) {
                u32 v = p[k];
                float lo = bf2f_lo(v), hi = bf2f_hi(v);
                float a0 = half ? hi : lo;
                float a1 = half ? lo : hi;
                int ld = (int)(sv[k] & (BN - 1));
                float* bp = &acc[ld * DIM + 2 * d2];
                atomicAdd(bp + half, a0);
                atomicAdd(bp + 1 - half, a1);
            }
        }
    }
}

// Mid layer: next_table[dst] = bf16(w^2 * sum of prescaled neighbor rows).
// INS/OUTS = row strides in u32 (32 = flat table, 64 = e1b parked in out region).
template<int INS, int OUTS>
__global__ void __launch_bounds__(1024) scat_mid(
        const u32* __restrict__ slab, const int* __restrict__ cursor,
        const float* __restrict__ dis, const u32* __restrict__ tab,
        u32* __restrict__ outt, int N, int CAP) {
    __shared__ float acc[BN * DIM];              // 128 KB, 1 WG/CU
    int b = blockIdx.x, tid = threadIdx.x;
    float4* az = (float4*)acc;
    for (int i = tid; i < BN * DIM / 4; i += 1024)
        az[i] = make_float4(0.f, 0.f, 0.f, 0.f);
    __syncthreads();
    int cnt = cursor[b];
    const u32* sp = slab + (size_t)b * CAP;
    scat_accum<INS>(sp, cnt, tab, acc, tid);
    __syncthreads();
    int nodeBase = b << BSH;
    int nLoc = min(BN, N - nodeBase);
    int tot = nLoc * 32;
    for (int i = tid; i < tot; i += 1024) {
        int nd = i >> 5, dd = i & 31;
        float w = dis[nodeBase + nd];
        float ww = w * w;
        float2 xy = *(const float2*)&acc[nd * DIM + 2 * dd];
        outt[(size_t)(nodeBase + nd) * OUTS + dd] = pack2(ww * xy.x, ww * xy.y);
    }
}

// Final layer fused with the mean epilogue:
// out = 0.25 * (e0 + (e1b + e2b)/w + w * acc).
// e1b lives in the first 128 B of each 256-B out row, so q1 is loaded for ALL of
// this thread's elements (pass 1) and drained with vmcnt(0) before any out store.
__global__ void __launch_bounds__(1024) scat_final(
        const u32* __restrict__ slab, const int* __restrict__ cursor,
        const float* __restrict__ dis, const u32* __restrict__ tab /* e2b, stride 32 */,
        const u32* __restrict__ e1b /* stride 64, aliases out rows */,
        const float2* __restrict__ emb0, float2* __restrict__ out, int N, int CAP) {
    __shared__ float acc[BN * DIM];
    int b = blockIdx.x, tid = threadIdx.x;
    float4* az = (float4*)acc;
    for (int i = tid; i < BN * DIM / 4; i += 1024)
        az[i] = make_float4(0.f, 0.f, 0.f, 0.f);
    __syncthreads();
    int cnt = cursor[b];
    const u32* sp = slab + (size_t)b * CAP;
    scat_accum<32>(sp, cnt, tab, acc, tid);
    __syncthreads();
    int nodeBase = b << BSH;
    int nLoc = min(BN, N - nodeBase);
    int tot = nLoc * 32;                         // <= 16384 = 16 * 1024
    u32 q1a[16];
#pragma unroll
    for (int k = 0; k < 16; ++k) {               // pass 1: read e1b before any write
        int i = tid + k * 1024;
        int nd = i >> 5, dd = i & 31;
        q1a[k] = (i < tot) ? e1b[(size_t)(nodeBase + nd) * 64 + dd] : 0u;
    }
    asm volatile("s_waitcnt vmcnt(0)" ::: "memory");
#pragma unroll
    for (int k = 0; k < 16; ++k) {               // pass 2: compute + overwrite rows
        int i = tid + k * 1024;
        if (i < tot) {
            int nd = i >> 5, dd = i & 31;
            int gn = nodeBase + nd;
            float w = dis[gn];
            float inv = (w > 0.f) ? 1.0f / w : 0.f;
            float2 xy = *(const float2*)&acc[nd * DIM + 2 * dd];
            u32 q1 = q1a[k];
            u32 q2 = tab[(size_t)gn * 32 + dd];
            float2 e0 = emb0[(size_t)gn * 32 + dd];
            float ox = 0.25f * (e0.x + (bf2f_lo(q1) + bf2f_lo(q2)) * inv + w * xy.x);
            float oy = 0.25f * (e0.y + (bf2f_hi(q1) + bf2f_hi(q2)) * inv + w * xy.y);
            out[(size_t)gn * 32 + dd] = make_float2(ox, oy);
        }
    }
}

extern "C" void kernel_launch(void* const* d_in, const int* in_sizes, int n_in,
                              void* d_out, int out_size, void* d_ws, size_t ws_size,
                              hipStream_t stream) {
    const int*   edge  = (const int*)d_in[0];
    const float* emb_w = (const float*)d_in[1];
    const int E = in_sizes[0] / 2;
    const int N = in_sizes[1] / DIM;
    const int* src = edge;         // edge_index[0]
    const int* dst = edge + E;     // edge_index[1]

    const int NB  = (N + BN - 1) >> BSH;          // <= 256
    const int nCh = (E + CHUNK - 1) / CHUNK;
    const int CAP = (E / (NB > 0 ? NB : 1)) * 2;  // 2x mean bucket load (uniform dst)

    float* out_base = (float*)d_out;
    float* emb0_out = out_base;                       // first half of d_out
    float* accf     = out_base + (size_t)N * DIM;     // second half -> out
    u32*   e1b      = (u32*)accf;                     // e1b row n = first 128 B of out row n

    // ws: [dis: N][cursor: 256][T0: N*32 u32 (e0b, later e2b)][slab: NB*CAP u32]
    // total ~32 MB (< the ~40 MB the previous layout proved available).
    float* dis    = (float*)d_ws;
    int*   cursor = (int*)(dis + ((N + 1) & ~1));
    u32*   T0     = (u32*)(cursor + 256);
    u32*   slab   = T0 + (size_t)N * 32;

    const int n4  = N * DIM / 4;
    const int BLK = 256;
    const int g4  = (n4 + BLK - 1) / BLK;

    // --- build: bucket edges + degrees (no sort, no col[]) ---
    zero_cur<<<1, 256, 0, stream>>>(cursor);
    c1_scatter<<<nCh, 512, 0, stream>>>(src, dst, cursor, slab, E, CAP);
    c2_deg<<<NB, 256, 0, stream>>>(slab, cursor, dis, N, CAP);

    // Prescaled bf16 table + exact emb0 output.
    cvt_copy<<<g4, BLK, 0, stream>>>((const float4*)emb_w, dis,
                                     (ushort4*)T0, (float4*)emb0_out, n4);

    // Layer 1: e1b = bf16(w^2 * sum(T0 rows))   (parked in out region, stride 64)
    scat_mid<32, 64><<<NB, 1024, 0, stream>>>(slab, cursor, dis, T0, e1b, N, CAP);
    // Layer 2: e2b -> T0 (e0b dead)
    scat_mid<64, 32><<<NB, 1024, 0, stream>>>(slab, cursor, dis, e1b, T0, N, CAP);
    // Layer 3 + mean epilogue (overwrites e1b rows with final out)
    scat_final<<<NB, 1024, 0, stream>>>(slab, cursor, dis, T0, e1b,
                                        (const float2*)emb_w, (float2*)accf, N, CAP);
}

// Round 2
// 280.475 us; speedup vs baseline: 8.1768x; 8.1768x over previous
//
#include <hip/hip_runtime.h>

// LightGCN forward on MI355X — slab-bucketed CSR build + split main/tail bf16 gather.
// Inputs: d_in[0] = edge_index int32 [2, E]; d_in[1] = emb_weight f32 [N, 64].
// Output: d_out = [emb0 (N*64) | out (N*64)] f32, out = mean(emb0..emb3).
// Assumes N <= 131072 (<=256 buckets). Here N=120000, E=2M, dst ~uniform.
//
// R1 note: LDS-scatter-accumulate variant (128KB acc/WG, ds atomics) measured
// 727 µs/layer at 3% VALU / 2.8% HBM — LDS-atomic serialization at 1 WG/CU.
// Reverted to the register-accumulating gather. This round: build-phase latency
// fixes only (c1 CHUNK 8192->4096 for 2 WGs/CU overlap; c3 256->512 threads).

#define DIM 64
#define BN 512          // nodes per bucket
#define BSH 9
#define CHUNK 4096      // edges per scatter workgroup (was 8192: 1 WG/CU, no overlap)

typedef unsigned short u16;
typedef unsigned int u32;

static __device__ __forceinline__ float bf2f_lo(u32 p) { return __uint_as_float(p << 16); }
static __device__ __forceinline__ float bf2f_hi(u32 p) { return __uint_as_float(p & 0xffff0000u); }
static __device__ __forceinline__ u16 f2bf(float f) {   // round-to-nearest-even
    unsigned u = __float_as_uint(f);
    return (u16)((u + 0x7fffu + ((u >> 16) & 1u)) >> 16);
}
static __device__ __forceinline__ u32 pack2(float a, float b) {
    return (u32)f2bf(a) | ((u32)f2bf(b) << 16);
}

__global__ void zero_cur(int* __restrict__ cursor) { cursor[threadIdx.x] = 0; }

// Per-chunk LDS counting-sort by bucket; slab space reserved with one global
// atomicAdd per (chunk,bucket). CHUNK=4096 -> 489 WGs (~2/CU): a co-resident
// WG hides this WG's barrier-chain latency (hist->scan->place->write).
__global__ void __launch_bounds__(512) c1_scatter(
        const int* __restrict__ src, const int* __restrict__ dst,
        int* __restrict__ cursor, u32* __restrict__ slab, int E, int CAP) {
    __shared__ u32 buf[CHUNK];
    __shared__ unsigned char bb[CHUNK];
    __shared__ int posb[256], startb[256], gbase[256];
    int w = blockIdx.x, tid = threadIdx.x;
    int lo = w * CHUNK, hi = min(lo + CHUNK, E);
    if (tid < 256) posb[tid] = 0;
    __syncthreads();
    for (int i = lo + tid; i < hi; i += 512) atomicAdd(&posb[dst[i] >> BSH], 1);
    __syncthreads();
    int x = 0;
    if (tid < 256) {
        x = posb[tid];
        gbase[tid] = x ? atomicAdd(cursor + tid, x) : 0;   // slab reservation
    }
    __syncthreads();
    for (int off = 1; off < 256; off <<= 1) {              // in-place scan of posb
        int t = (tid >= off && tid < 256) ? posb[tid - off] : 0;
        __syncthreads();
        if (tid < 256) posb[tid] += t;
        __syncthreads();
    }
    if (tid < 256) startb[tid] = posb[tid] - x;
    __syncthreads();
    if (tid < 256) posb[tid] = startb[tid];                // placement cursor
    __syncthreads();
    for (int i = lo + tid; i < hi; i += 512) {
        int d = dst[i], b = d >> BSH;
        int q = atomicAdd(&posb[b], 1);
        buf[q] = ((u32)src[i] << BSH) | (u32)(d & (BN - 1));
        bb[q] = (unsigned char)b;
    }
    __syncthreads();
    int n = hi - lo;
    for (int q = tid; q < n; q += 512) {                   // coalesced bucket-run writes
        int b = bb[q];
        slab[(size_t)b * CAP + gbase[b] + (q - startb[b])] = buf[q];
    }
}

// One WG per bucket: bucket_lo scan -> node-hist -> scan -> dis/row_se -> col.
// 512 threads (was 256): halves the histogram and placement phases (~17 vs ~34
// strided rounds over the bucket's ~8500 edges); node scan is 1 thread/node.
__global__ void __launch_bounds__(512) c3_build(
        const u32* __restrict__ slab, const int* __restrict__ cursor,
        int* __restrict__ col, int2* __restrict__ row_se, float* __restrict__ dis,
        int N, int CAP, int NB) {
    __shared__ int cur[BN];
    __shared__ int ps[512];
    int b = blockIdx.x, tid = threadIdx.x;
    // exclusive prefix of bucket counts -> this bucket's lo (first 256 threads)
    int xc = (tid < NB) ? cursor[tid] : 0;
    if (tid < 256) ps[tid] = xc;
    __syncthreads();
    for (int off = 1; off < 256; off <<= 1) {
        int t = (tid >= off && tid < 256) ? ps[tid - off] : 0;
        __syncthreads();
        if (tid < 256) ps[tid] += t;
        __syncthreads();
    }
    int lo  = b ? ps[b - 1] : 0;
    int cnt = cursor[b];
    __syncthreads();

    int nodeBase = b << BSH;
    int nLoc = min(BN, N - nodeBase);
    const u32* sp = slab + (size_t)b * CAP;
    cur[tid] = 0;                                          // 512 nodes, 512 threads
    __syncthreads();
    for (int i = tid; i < cnt; i += 512) atomicAdd(&cur[sp[i] & (BN - 1)], 1);
    __syncthreads();
    int c0 = cur[tid];
    ps[tid] = c0;
    __syncthreads();
    for (int off = 1; off < 512; off <<= 1) {              // scan of node counts
        int t = (tid >= off) ? ps[tid - off] : 0;
        __syncthreads();
        ps[tid] += t;
        __syncthreads();
    }
    int base = ps[tid] - c0;                               // exclusive
    cur[tid] = base;                                       // placement cursor
    if (tid < nLoc) {
        dis[nodeBase + tid] = c0 ? rsqrtf((float)c0) : 0.f;
        row_se[nodeBase + tid] = make_int2(lo + base, lo + base + c0);
    }
    __syncthreads();
    for (int i = tid; i < cnt; i += 512) {
        u32 v = sp[i];
        int q = atomicAdd(&cur[v & (BN - 1)], 1);
        col[lo + q] = (int)(v >> BSH);       // confined to this WG's region
    }
}

// e0b = bf16(dis * emb0) prescaled table; also emits the exact f32 emb0 output.
__global__ void cvt_copy(const float4* __restrict__ emb, const float* __restrict__ dis,
                         ushort4* __restrict__ e0b, float4* __restrict__ emb0_out, int n4) {
    int i = blockIdx.x * blockDim.x + threadIdx.x;
    if (i < n4) {
        float4 v = emb[i];
        float w = dis[i >> 4];
        ushort4 o;
        o.x = f2bf(w * v.x); o.y = f2bf(w * v.y);
        o.z = f2bf(w * v.z); o.w = f2bf(w * v.w);
        e0b[i] = o;
        emb0_out[i] = v;
    }
}

// Row accumulation: unpredicated full 16-edge rounds (8 chains/lane-half in
// flight, zero predication VALU) + ONE predicated tail round (index clamped to
// end-1 — same line as the valid last edge; loaded word zeroed by one cndmask).
#define GATHER_BODY(CURTAB)                                                    \
    float sx = 0.f, sy = 0.f;                                                  \
    int j = start;                                                             \
    for (; j + 16 <= end; j += 16) {                                           \
        int jj = j + half;                                                     \
        _Pragma("unroll")                                                      \
        for (int k = 0; k < 8; ++k) {                                          \
            u32 p = (CURTAB)[col[jj + 2 * k] * 32 + d2];                       \
            sx += bf2f_lo(p);                                                  \
            sy += bf2f_hi(p);                                                  \
        }                                                                      \
    }                                                                          \
    if (j < end) {                                                             \
        int endm1 = end - 1;                                                   \
        int jj = j + half;                                                     \
        _Pragma("unroll")                                                      \
        for (int k = 0; k < 8; ++k) {                                          \
            int e  = jj + 2 * k;                                               \
            u32 p  = (CURTAB)[col[min(e, endm1)] * 32 + d2];                   \
            if (e >= end) p = 0;                                               \
            sx += bf2f_lo(p);                                                  \
            sy += bf2f_hi(p);                                                  \
        }                                                                      \
    }                                                                          \
    sx += __shfl_xor(sx, 32);                                                  \
    sy += __shfl_xor(sy, 32);

// One wave per node; halves process even/odd edges of the SAME node.
// cur is the PRESCALED table (dis ⊙ e). Writes next = bf16(w*e) only.
__global__ void __launch_bounds__(256) gather_mid(
        const int2* __restrict__ row_se, const int* __restrict__ col,
        const float* __restrict__ dis, const u32* __restrict__ cur,
        u32* __restrict__ next, int N) {
    int t = blockIdx.x * blockDim.x + threadIdx.x;
    int wave = t >> 6, lane = t & 63;
    if (wave >= N) return;
    int half = lane >> 5, d2 = lane & 31;
    int2 se = row_se[wave];
    int start = __builtin_amdgcn_readfirstlane(se.x);
    int end   = __builtin_amdgcn_readfirstlane(se.y);
    GATHER_BODY(cur)
    float w = dis[wave];
    if (half == 0) next[wave * 32 + d2] = pack2(w * w * sx, w * w * sy);
}

// Final gather (layer 3) fused with the mean epilogue:
// out = 0.25 * (e0 + (e1b + e2b)/w + e3),  e3 = w * sum(prescaled e2b neighbors).
__global__ void __launch_bounds__(256) gather_final(
        const int2* __restrict__ row_se, const int* __restrict__ col,
        const float* __restrict__ dis, const u32* __restrict__ cur /* e2b */,
        const u32* __restrict__ e1b, const float2* __restrict__ emb0,
        float2* __restrict__ out, int N) {
    int t = blockIdx.x * blockDim.x + threadIdx.x;
    int wave = t >> 6, lane = t & 63;
    if (wave >= N) return;
    int half = lane >> 5, d2 = lane & 31;
    int2 se = row_se[wave];
    int start = __builtin_amdgcn_readfirstlane(se.x);
    int end   = __builtin_amdgcn_readfirstlane(se.y);
    GATHER_BODY(cur)
    if (half == 0) {
        float w = dis[wave];
        float inv = (w > 0.f) ? 1.0f / w : 0.f;
        float ex = w * sx, ey = w * sy;              // e3 dims
        int idx = wave * 32 + d2;
        u32 q1 = e1b[idx], q2 = cur[idx];
        float2 e0 = emb0[idx];
        float ox = 0.25f * (e0.x + (bf2f_lo(q1) + bf2f_lo(q2)) * inv + ex);
        float oy = 0.25f * (e0.y + (bf2f_hi(q1) + bf2f_hi(q2)) * inv + ey);
        out[idx] = make_float2(ox, oy);
    }
}

extern "C" void kernel_launch(void* const* d_in, const int* in_sizes, int n_in,
                              void* d_out, int out_size, void* d_ws, size_t ws_size,
                              hipStream_t stream) {
    const int*   edge  = (const int*)d_in[0];
    const float* emb_w = (const float*)d_in[1];
    const int E = in_sizes[0] / 2;
    const int N = in_sizes[1] / DIM;
    const int* src = edge;         // edge_index[0]
    const int* dst = edge + E;     // edge_index[1]

    const int NB  = (N + BN - 1) >> BSH;          // <= 256
    const int nCh = (E + CHUNK - 1) / CHUNK;
    const int CAP = (E / (NB > 0 ? NB : 1)) * 2;  // 2x mean bucket load (uniform dst)

    float* out_base = (float*)d_out;
    float* emb0_out = out_base;                       // first half of d_out
    float* acc      = out_base + (size_t)N * DIM;     // second half -> out

    // ws: [dis: N][row_se: N int2][cursor: 256][col: E]
    //     [zone: slab (NB*CAP u32) overlaid later by e0b|e1b (2 * N*64 u16)]
    float* dis       = (float*)d_ws;
    int2*  row_se    = (int2*)(dis + ((N + 1) & ~1));
    int*   cursor    = (int*)(row_se + N);
    int*   col       = cursor + 256;
    u32*   slab      = (u32*)(col + E);
    u16*   e0b       = (u16*)slab;                    // overlays slab (dead after c3)
    u16*   e1b       = e0b + (size_t)N * DIM;

    const int n4  = N * DIM / 4;
    const int BLK = 256;
    const int g4  = (n4 + BLK - 1) / BLK;
    const int gW  = (N * DIM + BLK - 1) / BLK;        // one 64-lane wave per node

    // --- CSR build ---
    zero_cur<<<1, 256, 0, stream>>>(cursor);
    c1_scatter<<<nCh, 512, 0, stream>>>(src, dst, cursor, slab, E, CAP);
    c3_build<<<NB, 512, 0, stream>>>(slab, cursor, col, row_se, dis, N, CAP, NB);

    // Prescaled bf16 table + exact emb0 output (slab dead now).
    cvt_copy<<<g4, BLK, 0, stream>>>((const float4*)emb_w, dis,
                                     (ushort4*)e0b, (float4*)emb0_out, n4);

    // Layer 1: e1b = bf16(w*e1)
    gather_mid<<<gW, BLK, 0, stream>>>(row_se, col, dis, (const u32*)e0b, (u32*)e1b, N);
    // Layer 2: e2b = bf16(w*e2)  (e0b region reused as output)
    gather_mid<<<gW, BLK, 0, stream>>>(row_se, col, dis, (const u32*)e1b, (u32*)e0b, N);
    // Layer 3 + mean epilogue
    gather_final<<<gW, BLK, 0, stream>>>(row_se, col, dis, (const u32*)e0b, (const u32*)e1b,
                                         (const float2*)emb_w, (float2*)acc, N);
}

// Round 4
// 262.457 us; speedup vs baseline: 8.7382x; 1.0687x over previous
//
#include <hip/hip_runtime.h>

// LightGCN forward on MI355X — slab-bucketed CSR build + paired-node dwordx2 gather.
// Inputs: d_in[0] = edge_index int32 [2, E]; d_in[1] = emb_weight f32 [N, 64].
// Output: d_out = [emb0 (N*64) | out (N*64)] f32, out = mean(emb0..emb3).
// Assumes N <= 131072 (<=256 buckets). Here N=120000, E=2M, dst ~uniform.
//
// R1 note: LDS-scatter-accumulate variant (128KB acc/WG, ds atomics) measured
// 727 µs/layer at 3% VALU / 2.8% HBM — LDS-atomic serialization at 1 WG/CU. Reverted.
// R2: gather loop rewritten — 2 nodes/wave (one per 32-lane half),
// two 16-lane subgroups per half fetch full 128-B rows as dwordx2 (4 dims/lane).
// One round = 4 col + 4 row loads for 16 edges (half the load insts), 8-edge
// round granularity per node (less Poisson-tail slot waste), waves halved.
// R3: container infra failure (no counters) — resubmitting identical R2 kernel.

#define DIM 64
#define BN 512          // nodes per bucket
#define BSH 9
#define CHUNK 4096      // edges per scatter workgroup (2 WGs/CU overlap)

typedef unsigned short u16;
typedef unsigned int u32;

static __device__ __forceinline__ float bf2f_lo(u32 p) { return __uint_as_float(p << 16); }
static __device__ __forceinline__ float bf2f_hi(u32 p) { return __uint_as_float(p & 0xffff0000u); }
static __device__ __forceinline__ u16 f2bf(float f) {   // round-to-nearest-even
    unsigned u = __float_as_uint(f);
    return (u16)((u + 0x7fffu + ((u >> 16) & 1u)) >> 16);
}
static __device__ __forceinline__ u32 pack2(float a, float b) {
    return (u32)f2bf(a) | ((u32)f2bf(b) << 16);
}

__global__ void zero_cur(int* __restrict__ cursor) { cursor[threadIdx.x] = 0; }

// Per-chunk LDS counting-sort by bucket; slab space reserved with one global
// atomicAdd per (chunk,bucket). Unchanged (verified in R1).
__global__ void __launch_bounds__(512) c1_scatter(
        const int* __restrict__ src, const int* __restrict__ dst,
        int* __restrict__ cursor, u32* __restrict__ slab, int E, int CAP) {
    __shared__ u32 buf[CHUNK];
    __shared__ unsigned char bb[CHUNK];
    __shared__ int posb[256], startb[256], gbase[256];
    int w = blockIdx.x, tid = threadIdx.x;
    int lo = w * CHUNK, hi = min(lo + CHUNK, E);
    if (tid < 256) posb[tid] = 0;
    __syncthreads();
    for (int i = lo + tid; i < hi; i += 512) atomicAdd(&posb[dst[i] >> BSH], 1);
    __syncthreads();
    int x = 0;
    if (tid < 256) {
        x = posb[tid];
        gbase[tid] = x ? atomicAdd(cursor + tid, x) : 0;   // slab reservation
    }
    __syncthreads();
    for (int off = 1; off < 256; off <<= 1) {              // in-place scan of posb
        int t = (tid >= off && tid < 256) ? posb[tid - off] : 0;
        __syncthreads();
        if (tid < 256) posb[tid] += t;
        __syncthreads();
    }
    if (tid < 256) startb[tid] = posb[tid] - x;
    __syncthreads();
    if (tid < 256) posb[tid] = startb[tid];                // placement cursor
    __syncthreads();
    for (int i = lo + tid; i < hi; i += 512) {
        int d = dst[i], b = d >> BSH;
        int q = atomicAdd(&posb[b], 1);
        buf[q] = ((u32)src[i] << BSH) | (u32)(d & (BN - 1));
        bb[q] = (unsigned char)b;
    }
    __syncthreads();
    int n = hi - lo;
    for (int q = tid; q < n; q += 512) {                   // coalesced bucket-run writes
        int b = bb[q];
        slab[(size_t)b * CAP + gbase[b] + (q - startb[b])] = buf[q];
    }
}

// One WG per bucket: bucket_lo scan -> node-hist -> scan -> dis/row_se -> col.
__global__ void __launch_bounds__(512) c3_build(
        const u32* __restrict__ slab, const int* __restrict__ cursor,
        int* __restrict__ col, int2* __restrict__ row_se, float* __restrict__ dis,
        int N, int CAP, int NB) {
    __shared__ int cur[BN];
    __shared__ int ps[512];
    int b = blockIdx.x, tid = threadIdx.x;
    // exclusive prefix of bucket counts -> this bucket's lo (first 256 threads)
    int xc = (tid < NB) ? cursor[tid] : 0;
    if (tid < 256) ps[tid] = xc;
    __syncthreads();
    for (int off = 1; off < 256; off <<= 1) {
        int t = (tid >= off && tid < 256) ? ps[tid - off] : 0;
        __syncthreads();
        if (tid < 256) ps[tid] += t;
        __syncthreads();
    }
    int lo  = b ? ps[b - 1] : 0;
    int cnt = cursor[b];
    __syncthreads();

    int nodeBase = b << BSH;
    int nLoc = min(BN, N - nodeBase);
    const u32* sp = slab + (size_t)b * CAP;
    cur[tid] = 0;                                          // 512 nodes, 512 threads
    __syncthreads();
    for (int i = tid; i < cnt; i += 512) atomicAdd(&cur[sp[i] & (BN - 1)], 1);
    __syncthreads();
    int c0 = cur[tid];
    ps[tid] = c0;
    __syncthreads();
    for (int off = 1; off < 512; off <<= 1) {              // scan of node counts
        int t = (tid >= off) ? ps[tid - off] : 0;
        __syncthreads();
        ps[tid] += t;
        __syncthreads();
    }
    int base = ps[tid] - c0;                               // exclusive
    cur[tid] = base;                                       // placement cursor
    if (tid < nLoc) {
        dis[nodeBase + tid] = c0 ? rsqrtf((float)c0) : 0.f;
        row_se[nodeBase + tid] = make_int2(lo + base, lo + base + c0);
    }
    __syncthreads();
    for (int i = tid; i < cnt; i += 512) {
        u32 v = sp[i];
        int q = atomicAdd(&cur[v & (BN - 1)], 1);
        col[lo + q] = (int)(v >> BSH);       // confined to this WG's region
    }
}

// e0b = bf16(dis * emb0) prescaled table; also emits the exact f32 emb0 output.
__global__ void cvt_copy(const float4* __restrict__ emb, const float* __restrict__ dis,
                         ushort4* __restrict__ e0b, float4* __restrict__ emb0_out, int n4) {
    int i = blockIdx.x * blockDim.x + threadIdx.x;
    if (i < n4) {
        float4 v = emb[i];
        float w = dis[i >> 4];
        ushort4 o;
        o.x = f2bf(w * v.x); o.y = f2bf(w * v.y);
        o.z = f2bf(w * v.z); o.w = f2bf(w * v.w);
        e0b[i] = o;
        emb0_out[i] = v;
    }
}

// Paired-node gather body. Wave = 2 nodes (lanes 0-31 / 32-63); within a half,
// subgroup g = (lane>>4)&1 handles edges j+2k+g, each lane loading dwordx2
// (dims 4d..4d+3) of the 128-B prescaled row. Main loop: unpredicated 8-edge
// rounds with per-half (divergent) bounds — exec-mask idles the shorter half.
// Tail: ONE predicated round, index clamped to end-1, loaded words zeroed.
// Reduce across g via shfl_xor(16); g==0 lanes (16/node) hold dims 4d..4d+3.
#define GATHER_BODY(CURTAB)                                                    \
    float s0 = 0.f, s1 = 0.f, s2 = 0.f, s3 = 0.f;                              \
    {                                                                          \
        int j = start;                                                         \
        for (; j + 8 <= end; j += 8) {                                         \
            _Pragma("unroll")                                                  \
            for (int k = 0; k < 4; ++k) {                                      \
                int c = col[j + 2 * k + g];                                    \
                uint2 p = *(const uint2*)((CURTAB) + (((size_t)c) << 5) + 2 * d); \
                s0 += bf2f_lo(p.x); s1 += bf2f_hi(p.x);                        \
                s2 += bf2f_lo(p.y); s3 += bf2f_hi(p.y);                        \
            }                                                                  \
        }                                                                      \
        if (j < end) {                                                         \
            int endm1 = end - 1;                                               \
            _Pragma("unroll")                                                  \
            for (int k = 0; k < 4; ++k) {                                      \
                int e = j + 2 * k + g;                                         \
                int c = col[min(e, endm1)];                                    \
                uint2 p = *(const uint2*)((CURTAB) + (((size_t)c) << 5) + 2 * d); \
                if (e >= end) { p.x = 0; p.y = 0; }                            \
                s0 += bf2f_lo(p.x); s1 += bf2f_hi(p.x);                        \
                s2 += bf2f_lo(p.y); s3 += bf2f_hi(p.y);                        \
            }                                                                  \
        }                                                                      \
    }                                                                          \
    s0 += __shfl_xor(s0, 16); s1 += __shfl_xor(s1, 16);                        \
    s2 += __shfl_xor(s2, 16); s3 += __shfl_xor(s3, 16);

// cur is the PRESCALED table (dis ⊙ e). Writes next = bf16(w*e) only.
__global__ void __launch_bounds__(256) gather_mid(
        const int2* __restrict__ row_se, const int* __restrict__ col,
        const float* __restrict__ dis, const u32* __restrict__ cur,
        u32* __restrict__ next, int N) {
    int t = blockIdx.x * blockDim.x + threadIdx.x;
    int pair = t >> 6, lane = t & 63;
    if (2 * pair >= N) return;
    int node = 2 * pair + (lane >> 5);
    int g = (lane >> 4) & 1, d = lane & 15;
    bool valid = node < N;
    int2 se = valid ? row_se[node] : make_int2(0, 0);
    int start = se.x, end = se.y;
    GATHER_BODY(cur)
    if (valid && g == 0) {
        float w = dis[node], ww = w * w;
        uint2 o;
        o.x = pack2(ww * s0, ww * s1);
        o.y = pack2(ww * s2, ww * s3);
        *(uint2*)(next + (((size_t)node) << 5) + 2 * d) = o;
    }
}

// Final gather (layer 3) fused with the mean epilogue:
// out = 0.25 * (e0 + (e1b + e2b)/w + e3),  e3 = w * sum(prescaled e2b neighbors).
__global__ void __launch_bounds__(256) gather_final(
        const int2* __restrict__ row_se, const int* __restrict__ col,
        const float* __restrict__ dis, const u32* __restrict__ cur /* e2b */,
        const u32* __restrict__ e1b, const float* __restrict__ emb0,
        float* __restrict__ out, int N) {
    int t = blockIdx.x * blockDim.x + threadIdx.x;
    int pair = t >> 6, lane = t & 63;
    if (2 * pair >= N) return;
    int node = 2 * pair + (lane >> 5);
    int g = (lane >> 4) & 1, d = lane & 15;
    bool valid = node < N;
    int2 se = valid ? row_se[node] : make_int2(0, 0);
    int start = se.x, end = se.y;
    GATHER_BODY(cur)
    if (valid && g == 0) {
        float w = dis[node];
        float inv = (w > 0.f) ? 1.0f / w : 0.f;
        size_t idx = (((size_t)node) << 5) + 2 * d;        // u32 units
        uint2 q1 = *(const uint2*)(e1b + idx);
        uint2 q2 = *(const uint2*)(cur + idx);
        float4 e0 = *(const float4*)(emb0 + 2 * idx);      // node*64 + 4d floats
        float4 r;
        r.x = 0.25f * (e0.x + (bf2f_lo(q1.x) + bf2f_lo(q2.x)) * inv + w * s0);
        r.y = 0.25f * (e0.y + (bf2f_hi(q1.x) + bf2f_hi(q2.x)) * inv + w * s1);
        r.z = 0.25f * (e0.z + (bf2f_lo(q1.y) + bf2f_lo(q2.y)) * inv + w * s2);
        r.w = 0.25f * (e0.w + (bf2f_hi(q1.y) + bf2f_hi(q2.y)) * inv + w * s3);
        *(float4*)(out + 2 * idx) = r;
    }
}

extern "C" void kernel_launch(void* const* d_in, const int* in_sizes, int n_in,
                              void* d_out, int out_size, void* d_ws, size_t ws_size,
                              hipStream_t stream) {
    const int*   edge  = (const int*)d_in[0];
    const float* emb_w = (const float*)d_in[1];
    const int E = in_sizes[0] / 2;
    const int N = in_sizes[1] / DIM;
    const int* src = edge;         // edge_index[0]
    const int* dst = edge + E;     // edge_index[1]

    const int NB  = (N + BN - 1) >> BSH;          // <= 256
    const int nCh = (E + CHUNK - 1) / CHUNK;
    const int CAP = (E / (NB > 0 ? NB : 1)) * 2;  // 2x mean bucket load (uniform dst)

    float* out_base = (float*)d_out;
    float* emb0_out = out_base;                       // first half of d_out
    float* acc      = out_base + (size_t)N * DIM;     // second half -> out

    // ws: [dis: N][row_se: N int2][cursor: 256][col: E]
    //     [zone: slab (NB*CAP u32) overlaid later by e0b|e1b (2 * N*64 u16)]
    float* dis       = (float*)d_ws;
    int2*  row_se    = (int2*)(dis + ((N + 1) & ~1));
    int*   cursor    = (int*)(row_se + N);
    int*   col       = cursor + 256;
    u32*   slab      = (u32*)(col + E);
    u16*   e0b       = (u16*)slab;                    // overlays slab (dead after c3)
    u16*   e1b       = e0b + (size_t)N * DIM;

    const int n4    = N * DIM / 4;
    const int BLK   = 256;
    const int g4    = (n4 + BLK - 1) / BLK;
    const int PAIRS = (N + 1) / 2;                    // 2 nodes per 64-lane wave
    const int gW    = (PAIRS * 64 + BLK - 1) / BLK;

    // --- CSR build ---
    zero_cur<<<1, 256, 0, stream>>>(cursor);
    c1_scatter<<<nCh, 512, 0, stream>>>(src, dst, cursor, slab, E, CAP);
    c3_build<<<NB, 512, 0, stream>>>(slab, cursor, col, row_se, dis, N, CAP, NB);

    // Prescaled bf16 table + exact emb0 output (slab dead now).
    cvt_copy<<<g4, BLK, 0, stream>>>((const float4*)emb_w, dis,
                                     (ushort4*)e0b, (float4*)emb0_out, n4);

    // Layer 1: e1b = bf16(w*e1)
    gather_mid<<<gW, BLK, 0, stream>>>(row_se, col, dis, (const u32*)e0b, (u32*)e1b, N);
    // Layer 2: e2b = bf16(w*e2)  (e0b region reused as output)
    gather_mid<<<gW, BLK, 0, stream>>>(row_se, col, dis, (const u32*)e1b, (u32*)e0b, N);
    // Layer 3 + mean epilogue
    gather_final<<<gW, BLK, 0, stream>>>(row_se, col, dis, (const u32*)e0b, (const u32*)e1b,
                                         emb_w, acc, N);
}

// Round 5
// 256.607 us; speedup vs baseline: 8.9374x; 1.0228x over previous
//
#include <hip/hip_runtime.h>

// LightGCN forward on MI355X — slab-bucketed CSR build + paired-node dwordx2 gather
// with explicit 2-stage software pipeline.
// Inputs: d_in[0] = edge_index int32 [2, E]; d_in[1] = emb_weight f32 [N, 64].
// Output: d_out = [emb0 (N*64) | out (N*64)] f32, out = mean(emb0..emb3).
// Assumes N <= 131072 (<=256 buckets). Here N=120000, E=2M, dst ~uniform.
//
// R1: LDS-scatter variant = 727 µs/layer (LDS-atomic serialization) — reverted.
// R2: 2 nodes/wave, 16-lane dwordx2 row loads: 53.3 -> 47.6 µs/gather, but
//     VALUBusy fell to 41% — loop is LATENCY-bound (4 rows in flight/lane,
//     col->row chain serialized per round).
// R4 (this round): software-pipeline the gather — issue round r+1's col+row
//     loads before accumulating round r (rows of 2 rounds in flight, ~8/lane).

#define DIM 64
#define BN 512          // nodes per bucket
#define BSH 9
#define CHUNK 4096      // edges per scatter workgroup (2 WGs/CU overlap)

typedef unsigned short u16;
typedef unsigned int u32;

static __device__ __forceinline__ float bf2f_lo(u32 p) { return __uint_as_float(p << 16); }
static __device__ __forceinline__ float bf2f_hi(u32 p) { return __uint_as_float(p & 0xffff0000u); }
static __device__ __forceinline__ u16 f2bf(float f) {   // round-to-nearest-even
    unsigned u = __float_as_uint(f);
    return (u16)((u + 0x7fffu + ((u >> 16) & 1u)) >> 16);
}
static __device__ __forceinline__ u32 pack2(float a, float b) {
    return (u32)f2bf(a) | ((u32)f2bf(b) << 16);
}

__global__ void zero_cur(int* __restrict__ cursor) { cursor[threadIdx.x] = 0; }

// Per-chunk LDS counting-sort by bucket; slab space reserved with one global
// atomicAdd per (chunk,bucket). Unchanged (verified in R1).
__global__ void __launch_bounds__(512) c1_scatter(
        const int* __restrict__ src, const int* __restrict__ dst,
        int* __restrict__ cursor, u32* __restrict__ slab, int E, int CAP) {
    __shared__ u32 buf[CHUNK];
    __shared__ unsigned char bb[CHUNK];
    __shared__ int posb[256], startb[256], gbase[256];
    int w = blockIdx.x, tid = threadIdx.x;
    int lo = w * CHUNK, hi = min(lo + CHUNK, E);
    if (tid < 256) posb[tid] = 0;
    __syncthreads();
    for (int i = lo + tid; i < hi; i += 512) atomicAdd(&posb[dst[i] >> BSH], 1);
    __syncthreads();
    int x = 0;
    if (tid < 256) {
        x = posb[tid];
        gbase[tid] = x ? atomicAdd(cursor + tid, x) : 0;   // slab reservation
    }
    __syncthreads();
    for (int off = 1; off < 256; off <<= 1) {              // in-place scan of posb
        int t = (tid >= off && tid < 256) ? posb[tid - off] : 0;
        __syncthreads();
        if (tid < 256) posb[tid] += t;
        __syncthreads();
    }
    if (tid < 256) startb[tid] = posb[tid] - x;
    __syncthreads();
    if (tid < 256) posb[tid] = startb[tid];                // placement cursor
    __syncthreads();
    for (int i = lo + tid; i < hi; i += 512) {
        int d = dst[i], b = d >> BSH;
        int q = atomicAdd(&posb[b], 1);
        buf[q] = ((u32)src[i] << BSH) | (u32)(d & (BN - 1));
        bb[q] = (unsigned char)b;
    }
    __syncthreads();
    int n = hi - lo;
    for (int q = tid; q < n; q += 512) {                   // coalesced bucket-run writes
        int b = bb[q];
        slab[(size_t)b * CAP + gbase[b] + (q - startb[b])] = buf[q];
    }
}

// One WG per bucket: bucket_lo scan -> node-hist -> scan -> dis/row_se -> col.
__global__ void __launch_bounds__(512) c3_build(
        const u32* __restrict__ slab, const int* __restrict__ cursor,
        int* __restrict__ col, int2* __restrict__ row_se, float* __restrict__ dis,
        int N, int CAP, int NB) {
    __shared__ int cur[BN];
    __shared__ int ps[512];
    int b = blockIdx.x, tid = threadIdx.x;
    // exclusive prefix of bucket counts -> this bucket's lo (first 256 threads)
    int xc = (tid < NB) ? cursor[tid] : 0;
    if (tid < 256) ps[tid] = xc;
    __syncthreads();
    for (int off = 1; off < 256; off <<= 1) {
        int t = (tid >= off && tid < 256) ? ps[tid - off] : 0;
        __syncthreads();
        if (tid < 256) ps[tid] += t;
        __syncthreads();
    }
    int lo  = b ? ps[b - 1] : 0;
    int cnt = cursor[b];
    __syncthreads();

    int nodeBase = b << BSH;
    int nLoc = min(BN, N - nodeBase);
    const u32* sp = slab + (size_t)b * CAP;
    cur[tid] = 0;                                          // 512 nodes, 512 threads
    __syncthreads();
    for (int i = tid; i < cnt; i += 512) atomicAdd(&cur[sp[i] & (BN - 1)], 1);
    __syncthreads();
    int c0 = cur[tid];
    ps[tid] = c0;
    __syncthreads();
    for (int off = 1; off < 512; off <<= 1) {              // scan of node counts
        int t = (tid >= off) ? ps[tid - off] : 0;
        __syncthreads();
        ps[tid] += t;
        __syncthreads();
    }
    int base = ps[tid] - c0;                               // exclusive
    cur[tid] = base;                                       // placement cursor
    if (tid < nLoc) {
        dis[nodeBase + tid] = c0 ? rsqrtf((float)c0) : 0.f;
        row_se[nodeBase + tid] = make_int2(lo + base, lo + base + c0);
    }
    __syncthreads();
    for (int i = tid; i < cnt; i += 512) {
        u32 v = sp[i];
        int q = atomicAdd(&cur[v & (BN - 1)], 1);
        col[lo + q] = (int)(v >> BSH);       // confined to this WG's region
    }
}

// e0b = bf16(dis * emb0) prescaled table; also emits the exact f32 emb0 output.
__global__ void cvt_copy(const float4* __restrict__ emb, const float* __restrict__ dis,
                         ushort4* __restrict__ e0b, float4* __restrict__ emb0_out, int n4) {
    int i = blockIdx.x * blockDim.x + threadIdx.x;
    if (i < n4) {
        float4 v = emb[i];
        float w = dis[i >> 4];
        ushort4 o;
        o.x = f2bf(w * v.x); o.y = f2bf(w * v.y);
        o.z = f2bf(w * v.z); o.w = f2bf(w * v.w);
        e0b[i] = o;
        emb0_out[i] = v;
    }
}

#define ACC4(P) { s0 += bf2f_lo((P).x); s1 += bf2f_hi((P).x);                  \
                  s2 += bf2f_lo((P).y); s3 += bf2f_hi((P).y); }

// Paired-node gather body, 2-stage software pipeline. Wave = 2 nodes (lane
// halves); subgroup g=(lane>>4)&1 handles edges j+2k+g; lane d=(lane&15) loads
// dwordx2 = dims 4d..4d+3 of the 128-B prescaled row. Pipeline: issue round
// r+1's 4 col + 4 row loads BEFORE accumulating round r's held rows — vmcnt is
// in-order, so accumulate waits only on the old rows while the new 8 loads stay
// in flight (~8 rows outstanding/lane vs 4 unpipelined). Numerically identical
// add order to R2. Tail: ONE predicated round, index clamped to end-1.
#define GATHER_BODY(CURTAB)                                                    \
    float s0 = 0.f, s1 = 0.f, s2 = 0.f, s3 = 0.f;                              \
    {                                                                          \
        int nfull = (end - start) >> 3;                                        \
        uint2 p0, p1, p2, p3;                                                  \
        if (nfull > 0) {                                                       \
            int j = start;                                                     \
            int a0 = col[j + g],     a1 = col[j + 2 + g];                      \
            int a2 = col[j + 4 + g], a3 = col[j + 6 + g];                      \
            p0 = *(const uint2*)((CURTAB) + (((size_t)a0) << 5) + 2 * d);      \
            p1 = *(const uint2*)((CURTAB) + (((size_t)a1) << 5) + 2 * d);      \
            p2 = *(const uint2*)((CURTAB) + (((size_t)a2) << 5) + 2 * d);      \
            p3 = *(const uint2*)((CURTAB) + (((size_t)a3) << 5) + 2 * d);      \
        }                                                                      \
        for (int r = 1; r < nfull; ++r) {                                      \
            int jn = start + 8 * r;                                            \
            int b0 = col[jn + g],     b1 = col[jn + 2 + g];                    \
            int b2 = col[jn + 4 + g], b3 = col[jn + 6 + g];                    \
            uint2 q0 = *(const uint2*)((CURTAB) + (((size_t)b0) << 5) + 2 * d);\
            uint2 q1 = *(const uint2*)((CURTAB) + (((size_t)b1) << 5) + 2 * d);\
            uint2 q2 = *(const uint2*)((CURTAB) + (((size_t)b2) << 5) + 2 * d);\
            uint2 q3 = *(const uint2*)((CURTAB) + (((size_t)b3) << 5) + 2 * d);\
            ACC4(p0) ACC4(p1) ACC4(p2) ACC4(p3)                                \
            p0 = q0; p1 = q1; p2 = q2; p3 = q3;                                \
        }                                                                      \
        if (nfull > 0) { ACC4(p0) ACC4(p1) ACC4(p2) ACC4(p3) }                 \
        int jt = start + 8 * nfull;                                            \
        if (jt < end) {                                                        \
            int endm1 = end - 1;                                               \
            _Pragma("unroll")                                                  \
            for (int k = 0; k < 4; ++k) {                                      \
                int e = jt + 2 * k + g;                                        \
                int c = col[min(e, endm1)];                                    \
                uint2 p = *(const uint2*)((CURTAB) + (((size_t)c) << 5) + 2 * d); \
                if (e >= end) { p.x = 0; p.y = 0; }                            \
                ACC4(p)                                                        \
            }                                                                  \
        }                                                                      \
    }                                                                          \
    s0 += __shfl_xor(s0, 16); s1 += __shfl_xor(s1, 16);                        \
    s2 += __shfl_xor(s2, 16); s3 += __shfl_xor(s3, 16);

// cur is the PRESCALED table (dis ⊙ e). Writes next = bf16(w*e) only.
__global__ void __launch_bounds__(256) gather_mid(
        const int2* __restrict__ row_se, const int* __restrict__ col,
        const float* __restrict__ dis, const u32* __restrict__ cur,
        u32* __restrict__ next, int N) {
    int t = blockIdx.x * blockDim.x + threadIdx.x;
    int pair = t >> 6, lane = t & 63;
    if (2 * pair >= N) return;
    int node = 2 * pair + (lane >> 5);
    int g = (lane >> 4) & 1, d = lane & 15;
    bool valid = node < N;
    int2 se = valid ? row_se[node] : make_int2(0, 0);
    int start = se.x, end = se.y;
    GATHER_BODY(cur)
    if (valid && g == 0) {
        float w = dis[node], ww = w * w;
        uint2 o;
        o.x = pack2(ww * s0, ww * s1);
        o.y = pack2(ww * s2, ww * s3);
        *(uint2*)(next + (((size_t)node) << 5) + 2 * d) = o;
    }
}

// Final gather (layer 3) fused with the mean epilogue:
// out = 0.25 * (e0 + (e1b + e2b)/w + e3),  e3 = w * sum(prescaled e2b neighbors).
__global__ void __launch_bounds__(256) gather_final(
        const int2* __restrict__ row_se, const int* __restrict__ col,
        const float* __restrict__ dis, const u32* __restrict__ cur /* e2b */,
        const u32* __restrict__ e1b, const float* __restrict__ emb0,
        float* __restrict__ out, int N) {
    int t = blockIdx.x * blockDim.x + threadIdx.x;
    int pair = t >> 6, lane = t & 63;
    if (2 * pair >= N) return;
    int node = 2 * pair + (lane >> 5);
    int g = (lane >> 4) & 1, d = lane & 15;
    bool valid = node < N;
    int2 se = valid ? row_se[node] : make_int2(0, 0);
    int start = se.x, end = se.y;
    GATHER_BODY(cur)
    if (valid && g == 0) {
        float w = dis[node];
        float inv = (w > 0.f) ? 1.0f / w : 0.f;
        size_t idx = (((size_t)node) << 5) + 2 * d;        // u32 units
        uint2 q1 = *(const uint2*)(e1b + idx);
        uint2 q2 = *(const uint2*)(cur + idx);
        float4 e0 = *(const float4*)(emb0 + 2 * idx);      // node*64 + 4d floats
        float4 r;
        r.x = 0.25f * (e0.x + (bf2f_lo(q1.x) + bf2f_lo(q2.x)) * inv + w * s0);
        r.y = 0.25f * (e0.y + (bf2f_hi(q1.x) + bf2f_hi(q2.x)) * inv + w * s1);
        r.z = 0.25f * (e0.z + (bf2f_lo(q1.y) + bf2f_lo(q2.y)) * inv + w * s2);
        r.w = 0.25f * (e0.w + (bf2f_hi(q1.y) + bf2f_hi(q2.y)) * inv + w * s3);
        *(float4*)(out + 2 * idx) = r;
    }
}

extern "C" void kernel_launch(void* const* d_in, const int* in_sizes, int n_in,
                              void* d_out, int out_size, void* d_ws, size_t ws_size,
                              hipStream_t stream) {
    const int*   edge  = (const int*)d_in[0];
    const float* emb_w = (const float*)d_in[1];
    const int E = in_sizes[0] / 2;
    const int N = in_sizes[1] / DIM;
    const int* src = edge;         // edge_index[0]
    const int* dst = edge + E;     // edge_index[1]

    const int NB  = (N + BN - 1) >> BSH;          // <= 256
    const int nCh = (E + CHUNK - 1) / CHUNK;
    const int CAP = (E / (NB > 0 ? NB : 1)) * 2;  // 2x mean bucket load (uniform dst)

    float* out_base = (float*)d_out;
    float* emb0_out = out_base;                       // first half of d_out
    float* acc      = out_base + (size_t)N * DIM;     // second half -> out

    // ws: [dis: N][row_se: N int2][cursor: 256][col: E]
    //     [zone: slab (NB*CAP u32) overlaid later by e0b|e1b (2 * N*64 u16)]
    float* dis       = (float*)d_ws;
    int2*  row_se    = (int2*)(dis + ((N + 1) & ~1));
    int*   cursor    = (int*)(row_se + N);
    int*   col       = cursor + 256;
    u32*   slab      = (u32*)(col + E);
    u16*   e0b       = (u16*)slab;                    // overlays slab (dead after c3)
    u16*   e1b       = e0b + (size_t)N * DIM;

    const int n4    = N * DIM / 4;
    const int BLK   = 256;
    const int g4    = (n4 + BLK - 1) / BLK;
    const int PAIRS = (N + 1) / 2;                    // 2 nodes per 64-lane wave
    const int gW    = (PAIRS * 64 + BLK - 1) / BLK;

    // --- CSR build ---
    zero_cur<<<1, 256, 0, stream>>>(cursor);
    c1_scatter<<<nCh, 512, 0, stream>>>(src, dst, cursor, slab, E, CAP);
    c3_build<<<NB, 512, 0, stream>>>(slab, cursor, col, row_se, dis, N, CAP, NB);

    // Prescaled bf16 table + exact emb0 output (slab dead now).
    cvt_copy<<<g4, BLK, 0, stream>>>((const float4*)emb_w, dis,
                                     (ushort4*)e0b, (float4*)emb0_out, n4);

    // Layer 1: e1b = bf16(w*e1)
    gather_mid<<<gW, BLK, 0, stream>>>(row_se, col, dis, (const u32*)e0b, (u32*)e1b, N);
    // Layer 2: e2b = bf16(w*e2)  (e0b region reused as output)
    gather_mid<<<gW, BLK, 0, stream>>>(row_se, col, dis, (const u32*)e1b, (u32*)e0b, N);
    // Layer 3 + mean epilogue
    gather_final<<<gW, BLK, 0, stream>>>(row_se, col, dis, (const u32*)e0b, (const u32*)e1b,
                                         emb_w, acc, N);
}